// Round 1
// baseline (48455.930 us; speedup 1.0000x reference)
//
#include <hip/hip_runtime.h>
#include <stdint.h>

// ---------------------------------------------------------------------------
// LIDM forward: 255 steps x 25-layer stacked LSTM wavefront.
// NOISE_VARIANT 0 = JAX threefry_partitionable (default in jax >= 0.5)
//               1 = legacy (pre-partitionable) split/random_bits
// ---------------------------------------------------------------------------
#ifndef NOISE_VARIANT
#define NOISE_VARIANT 0
#endif

#define S_ 256
#define B_ 64
#define O_ 128
#define L_ 256
#define NL_ 25

// workspace layout (floats)
#define E_MLP_OFF   0            // [S][L][B]   (k slot 0 unused)
#define E_MLP_SZ    (S_*L_*B_)                       // 4194304
#define H_STATE_OFF (E_MLP_OFF + E_MLP_SZ)           // [2][NL][L][B]
#define H_STATE_SZ  (2*NL_*L_*B_)                    // 819200
#define C_STATE_OFF (H_STATE_OFF + H_STATE_SZ)       // [NL][L][B]
#define C_STATE_SZ  (NL_*L_*B_)
#define H_EMB_OFF   (C_STATE_OFF + C_STATE_SZ)       // [NL][L][B]
#define H_EMB_SZ    (NL_*L_*B_)
#define HLAST_OFF   (H_EMB_OFF + H_EMB_SZ)           // [S][L][B] (also e1 temp)
#define HLAST_SZ    (S_*L_*B_)
#define WS_FLOATS   (HLAST_OFF + HLAST_SZ)           // 10,027,008 floats = 40.1 MB

// ---------------------------- threefry2x32 ---------------------------------
__device__ __forceinline__ uint32_t rotl32(uint32_t v, int r) {
  return (v << r) | (v >> (32 - r));
}

__device__ __forceinline__ void tf2x32(uint32_t k0, uint32_t k1,
                                       uint32_t x0, uint32_t x1,
                                       uint32_t& o0, uint32_t& o1) {
  uint32_t ks2 = k0 ^ k1 ^ 0x1BD11BDAu;
  x0 += k0; x1 += k1;
  x0 += x1; x1 = rotl32(x1, 13); x1 ^= x0;
  x0 += x1; x1 = rotl32(x1, 15); x1 ^= x0;
  x0 += x1; x1 = rotl32(x1, 26); x1 ^= x0;
  x0 += x1; x1 = rotl32(x1,  6); x1 ^= x0;
  x0 += k1; x1 += ks2 + 1u;
  x0 += x1; x1 = rotl32(x1, 17); x1 ^= x0;
  x0 += x1; x1 = rotl32(x1, 29); x1 ^= x0;
  x0 += x1; x1 = rotl32(x1, 16); x1 ^= x0;
  x0 += x1; x1 = rotl32(x1, 24); x1 ^= x0;
  x0 += ks2; x1 += k0 + 2u;
  x0 += x1; x1 = rotl32(x1, 13); x1 ^= x0;
  x0 += x1; x1 = rotl32(x1, 15); x1 ^= x0;
  x0 += x1; x1 = rotl32(x1, 26); x1 ^= x0;
  x0 += x1; x1 = rotl32(x1,  6); x1 ^= x0;
  x0 += k0; x1 += k1 + 3u;
  x0 += x1; x1 = rotl32(x1, 17); x1 ^= x0;
  x0 += x1; x1 = rotl32(x1, 29); x1 ^= x0;
  x0 += x1; x1 = rotl32(x1, 16); x1 ^= x0;
  x0 += x1; x1 = rotl32(x1, 24); x1 ^= x0;
  x0 += k1; x1 += ks2 + 4u;
  x0 += x1; x1 = rotl32(x1, 13); x1 ^= x0;
  x0 += x1; x1 = rotl32(x1, 15); x1 ^= x0;
  x0 += x1; x1 = rotl32(x1, 26); x1 ^= x0;
  x0 += x1; x1 = rotl32(x1,  6); x1 ^= x0;
  o0 = x0 + ks2; o1 = x1 + k0 + 5u;
}

// kh, kx = split(fold_in(key(42), k))
__device__ __forceinline__ void step_keys(int k, uint32_t& kh0, uint32_t& kh1,
                                          uint32_t& kx0, uint32_t& kx1) {
  uint32_t f0, f1;
  tf2x32(0u, 42u, 0u, (uint32_t)k, f0, f1);   // fold_in: TF(key, (0, k))
#if NOISE_VARIANT == 0
  tf2x32(f0, f1, 0u, 0u, kh0, kh1);           // split foldlike: TF(fk,(0,i))
  tf2x32(f0, f1, 0u, 1u, kx0, kx1);
#else
  uint32_t a0, a1, b0, b1;
  tf2x32(f0, f1, 0u, 2u, a0, a1);             // legacy split: pairs (0,2),(1,3)
  tf2x32(f0, f1, 1u, 3u, b0, b1);
  kh0 = a0; kh1 = b0; kx0 = a1; kx1 = b1;
#endif
}

// 32 random bits at flat index i of an array with `total` elements
__device__ __forceinline__ uint32_t rbits(uint32_t key0, uint32_t key1,
                                          uint32_t i, uint32_t total) {
#if NOISE_VARIANT == 0
  uint32_t b0, b1;
  tf2x32(key0, key1, 0u, i, b0, b1);
  (void)total;
  return b0 ^ b1;
#else
  uint32_t half = total >> 1;
  uint32_t x0 = (i < half) ? i : (i - half);
  uint32_t x1 = x0 + half;
  uint32_t b0, b1;
  tf2x32(key0, key1, x0, x1, b0, b1);
  return (i < half) ? b0 : b1;
#endif
}

// XLA-exact: uniform(lo=nextafter(-1,0), hi=1) -> sqrt(2)*erfinv(u)
__device__ __forceinline__ float u32_to_normal(uint32_t bits) {
  const float lo = __uint_as_float(0xBF7FFFFFu);  // -0.99999994
  float f = __uint_as_float((bits >> 9) | 0x3F800000u) - 1.0f;  // [0,1)
  float u = f * 2.0f + lo;    // (hi-lo) rounds to exactly 2.0f in fp32
  u = fmaxf(lo, u);
  float x = u;
  float w = -log1pf(-x * x);
  float p;
  if (w < 5.0f) {
    w -= 2.5f;
    p =            2.81022636e-08f;
    p = fmaf(p, w, 3.43273939e-07f);
    p = fmaf(p, w, -3.5233877e-06f);
    p = fmaf(p, w, -4.39150654e-06f);
    p = fmaf(p, w, 0.00021858087f);
    p = fmaf(p, w, -0.00125372503f);
    p = fmaf(p, w, -0.00417768164f);
    p = fmaf(p, w, 0.246640727f);
    p = fmaf(p, w, 1.50140941f);
  } else {
    w = sqrtf(w) - 3.0f;
    p =            -0.000200214257f;
    p = fmaf(p, w, 0.000100950558f);
    p = fmaf(p, w, 0.00134934322f);
    p = fmaf(p, w, -0.00367342844f);
    p = fmaf(p, w, 0.00573950773f);
    p = fmaf(p, w, -0.0076224613f);
    p = fmaf(p, w, 0.00943887047f);
    p = fmaf(p, w, 1.00167406f);
    p = fmaf(p, w, 2.83297682f);
  }
  float ei = p * x;
  return __uint_as_float(0x3FB504F3u) * ei;  // float32(sqrt(2))
}

__device__ __forceinline__ float sigm(float x) { return 1.0f / (1.0f + expf(-x)); }

// ------------------------------- kernels -----------------------------------

// h_state[0][n][m][b] = z0[n][b][m]; c_state = 0
__global__ __launch_bounds__(256) void k_init(const float* __restrict__ z0,
                                              float* __restrict__ h_state,
                                              float* __restrict__ c_state) {
  int idx = blockIdx.x * 256 + threadIdx.x;  // 0..409599
  int n = idx >> 14;
  int r = idx & 16383;
  int m = r >> 6;
  int b = r & 63;
  h_state[idx] = z0[((size_t)(n * B_ + b)) * L_ + m];
  c_state[idx] = 0.0f;
}

// e1[k][j][b] = relu(obsrv[k] @ Wx1^T + bx1)   (grid 255*4)
__global__ __launch_bounds__(256) void k_mlp1(const float* __restrict__ obsrv,
                                              const float* __restrict__ Wx1,
                                              const float* __restrict__ bx1,
                                              float* __restrict__ e1out) {
  int k = 1 + (blockIdx.x >> 2);
  int jc = blockIdx.x & 3;
  int lane = threadIdx.x & 63;
  int wv = threadIdx.x >> 6;
  int j0 = jc * 64 + wv * 16;
  const float* xrow = obsrv + ((size_t)k * B_ + lane) * O_;
  float acc[16];
#pragma unroll
  for (int i = 0; i < 16; ++i) acc[i] = 0.0f;
  for (int o = 0; o < O_; o += 4) {
    float4 a = *reinterpret_cast<const float4*>(&xrow[o]);
#pragma unroll
    for (int mi = 0; mi < 16; ++mi) {
      float4 wt = *reinterpret_cast<const float4*>(&Wx1[(size_t)(j0 + mi) * O_ + o]);
      float t = acc[mi];
      t = fmaf(a.x, wt.x, t); t = fmaf(a.y, wt.y, t);
      t = fmaf(a.z, wt.z, t); t = fmaf(a.w, wt.w, t);
      acc[mi] = t;
    }
  }
  float* dst = e1out + (size_t)k * L_ * B_;
#pragma unroll
  for (int mi = 0; mi < 16; ++mi) {
    float v = acc[mi] + bx1[j0 + mi];
    dst[(j0 + mi) * B_ + lane] = fmaxf(v, 0.0f);
  }
}

// layers 2+3 of MLP + sqrt(alpha)*e + 0.1*noise(kx)  (grid 255, 1 WG per k)
__global__ __launch_bounds__(256) void k_mlp2(const float* __restrict__ e1buf,
                                              const float* __restrict__ Wx2,
                                              const float* __restrict__ bx2,
                                              const float* __restrict__ Wx3,
                                              const float* __restrict__ bx3,
                                              float* __restrict__ E_mlp) {
  __shared__ float e2s[L_ * B_];  // 64 KB
  int k = 1 + blockIdx.x;
  int lane = threadIdx.x & 63;
  int wv = threadIdx.x >> 6;
  const float* e1 = e1buf + (size_t)k * L_ * B_;

  for (int rep = 0; rep < 4; ++rep) {
    int m0 = rep * 64 + wv * 16;
    float acc[16];
#pragma unroll
    for (int i = 0; i < 16; ++i) acc[i] = 0.0f;
    for (int j = 0; j < L_; j += 4) {
      float a0 = e1[(j + 0) * B_ + lane];
      float a1 = e1[(j + 1) * B_ + lane];
      float a2 = e1[(j + 2) * B_ + lane];
      float a3 = e1[(j + 3) * B_ + lane];
#pragma unroll
      for (int mi = 0; mi < 16; ++mi) {
        float4 wt = *reinterpret_cast<const float4*>(&Wx2[(size_t)(m0 + mi) * L_ + j]);
        float t = acc[mi];
        t = fmaf(a0, wt.x, t); t = fmaf(a1, wt.y, t);
        t = fmaf(a2, wt.z, t); t = fmaf(a3, wt.w, t);
        acc[mi] = t;
      }
    }
#pragma unroll
    for (int mi = 0; mi < 16; ++mi) {
      float v = acc[mi] + bx2[m0 + mi];
      e2s[(m0 + mi) * B_ + lane] = fmaxf(v, 0.0f);
    }
  }
  __syncthreads();

  uint32_t kh0, kh1, kx0, kx1;
  step_keys(k, kh0, kh1, kx0, kx1);
  const float sa = sqrtf(0.9f);
  float* dst = E_mlp + (size_t)k * L_ * B_;

  for (int rep = 0; rep < 4; ++rep) {
    int m0 = rep * 64 + wv * 16;
    float acc[16];
#pragma unroll
    for (int i = 0; i < 16; ++i) acc[i] = 0.0f;
    for (int j = 0; j < L_; j += 4) {
      float a0 = e2s[(j + 0) * B_ + lane];
      float a1 = e2s[(j + 1) * B_ + lane];
      float a2 = e2s[(j + 2) * B_ + lane];
      float a3 = e2s[(j + 3) * B_ + lane];
#pragma unroll
      for (int mi = 0; mi < 16; ++mi) {
        float4 wt = *reinterpret_cast<const float4*>(&Wx3[(size_t)(m0 + mi) * L_ + j]);
        float t = acc[mi];
        t = fmaf(a0, wt.x, t); t = fmaf(a1, wt.y, t);
        t = fmaf(a2, wt.z, t); t = fmaf(a3, wt.w, t);
        acc[mi] = t;
      }
    }
#pragma unroll
    for (int mi = 0; mi < 16; ++mi) {
      int m = m0 + mi;
      uint32_t bits = rbits(kx0, kx1, (uint32_t)(lane * L_ + m), (uint32_t)(B_ * L_));
      float nz = u32_to_normal(bits);
      float v = acc[mi] + bx3[m];
      dst[m * B_ + lane] = sa * v + 0.1f * nz;
    }
  }
}

// diagonal phase 1: h_emb[l] = h_state[(k-1)&1][l] @ W_emb^T + b_emb + 0.1*noise(kh)
__global__ __launch_bounds__(256) void k_emb(const float* __restrict__ h_state,
                                             const float* __restrict__ W_emb,
                                             const float* __restrict__ b_emb,
                                             float* __restrict__ h_emb,
                                             int d, int lmin) {
  int l = lmin + (blockIdx.x >> 2);
  int mc = blockIdx.x & 3;
  int k = d - l;
  int lane = threadIdx.x & 63;
  int wv = threadIdx.x >> 6;
  int m0 = mc * 64 + wv * 16;
  const float* hsrc = h_state + ((size_t)((k - 1) & 1) * NL_ + l) * (L_ * B_);
  float acc[16];
#pragma unroll
  for (int i = 0; i < 16; ++i) acc[i] = 0.0f;
  for (int j = 0; j < L_; j += 4) {
    float a0 = hsrc[(j + 0) * B_ + lane];
    float a1 = hsrc[(j + 1) * B_ + lane];
    float a2 = hsrc[(j + 2) * B_ + lane];
    float a3 = hsrc[(j + 3) * B_ + lane];
#pragma unroll
    for (int mi = 0; mi < 16; ++mi) {
      float4 wt = *reinterpret_cast<const float4*>(&W_emb[(size_t)(m0 + mi) * L_ + j]);
      float t = acc[mi];
      t = fmaf(a0, wt.x, t); t = fmaf(a1, wt.y, t);
      t = fmaf(a2, wt.z, t); t = fmaf(a3, wt.w, t);
      acc[mi] = t;
    }
  }
  uint32_t kh0, kh1, kx0, kx1;
  step_keys(k, kh0, kh1, kx0, kx1);
  float* dst = h_emb + (size_t)l * L_ * B_;
#pragma unroll
  for (int mi = 0; mi < 16; ++mi) {
    int m = m0 + mi;
    uint32_t i = ((uint32_t)(l * B_ + lane)) * L_ + (uint32_t)m;  // (n*B+b)*L+m
    float nz = u32_to_normal(rbits(kh0, kh1, i, (uint32_t)(NL_ * B_ * L_)));
    dst[m * B_ + lane] = acc[mi] + b_emb[m] + 0.1f * nz;
  }
}

// diagonal phase 2: gates + activations, update h/c state, stash Hlast
__global__ __launch_bounds__(256) void k_gates(float* __restrict__ h_state,
                                               float* __restrict__ c_state,
                                               const float* __restrict__ h_emb,
                                               const float* __restrict__ E_mlp,
                                               const float* __restrict__ W_ih,
                                               const float* __restrict__ W_hh,
                                               const float* __restrict__ b_ih,
                                               const float* __restrict__ b_hh,
                                               float* __restrict__ Hlast,
                                               int d, int lmin) {
  int l = lmin + (blockIdx.x >> 4);
  int mc = blockIdx.x & 15;
  int k = d - l;
  int lane = threadIdx.x & 63;
  int wv = threadIdx.x >> 6;
  int m0 = mc * 16 + wv * 4;

  float acc[4][4];
#pragma unroll
  for (int g = 0; g < 4; ++g)
#pragma unroll
    for (int mi = 0; mi < 4; ++mi) acc[g][mi] = 0.0f;

  const float* ein = (l == 0)
      ? (E_mlp + (size_t)k * L_ * B_)
      : (h_state + ((size_t)(k & 1) * NL_ + (l - 1)) * (L_ * B_));
  const float* Wl = W_ih + (size_t)l * 4 * L_ * L_;
  for (int j = 0; j < L_; j += 4) {
    float a0 = ein[(j + 0) * B_ + lane];
    float a1 = ein[(j + 1) * B_ + lane];
    float a2 = ein[(j + 2) * B_ + lane];
    float a3 = ein[(j + 3) * B_ + lane];
#pragma unroll
    for (int g = 0; g < 4; ++g)
#pragma unroll
      for (int mi = 0; mi < 4; ++mi) {
        float4 wt = *reinterpret_cast<const float4*>(&Wl[(size_t)(g * L_ + m0 + mi) * L_ + j]);
        float t = acc[g][mi];
        t = fmaf(a0, wt.x, t); t = fmaf(a1, wt.y, t);
        t = fmaf(a2, wt.z, t); t = fmaf(a3, wt.w, t);
        acc[g][mi] = t;
      }
  }
  const float* hem = h_emb + (size_t)l * L_ * B_;
  const float* Wl2 = W_hh + (size_t)l * 4 * L_ * L_;
  for (int j = 0; j < L_; j += 4) {
    float a0 = hem[(j + 0) * B_ + lane];
    float a1 = hem[(j + 1) * B_ + lane];
    float a2 = hem[(j + 2) * B_ + lane];
    float a3 = hem[(j + 3) * B_ + lane];
#pragma unroll
    for (int g = 0; g < 4; ++g)
#pragma unroll
      for (int mi = 0; mi < 4; ++mi) {
        float4 wt = *reinterpret_cast<const float4*>(&Wl2[(size_t)(g * L_ + m0 + mi) * L_ + j]);
        float t = acc[g][mi];
        t = fmaf(a0, wt.x, t); t = fmaf(a1, wt.y, t);
        t = fmaf(a2, wt.z, t); t = fmaf(a3, wt.w, t);
        acc[g][mi] = t;
      }
  }

  int bb = l * 4 * L_;
  float* hdst = h_state + ((size_t)(k & 1) * NL_ + l) * (L_ * B_);
#pragma unroll
  for (int mi = 0; mi < 4; ++mi) {
    int m = m0 + mi;
    float iv = acc[0][mi] + b_ih[bb + m]           + b_hh[bb + m];
    float fv = acc[1][mi] + b_ih[bb + L_ + m]      + b_hh[bb + L_ + m];
    float gv = acc[2][mi] + b_ih[bb + 2 * L_ + m]  + b_hh[bb + 2 * L_ + m];
    float ov = acc[3][mi] + b_ih[bb + 3 * L_ + m]  + b_hh[bb + 3 * L_ + m];
    size_t idx = ((size_t)l * L_ + m) * B_ + lane;
    float co = c_state[idx];
    float cn = sigm(fv) * co + sigm(iv) * tanhf(gv);
    float hn = sigm(ov) * tanhf(cn);
    c_state[idx] = cn;
    hdst[m * B_ + lane] = hn;
    if (l == NL_ - 1) Hlast[((size_t)k * L_ + m) * B_ + lane] = hn;
  }
}

// out[k][b][m] = Hlast[k] @ W_out^T + b_out ; out[0] = 0   (grid 256*4)
__global__ __launch_bounds__(256) void k_final(const float* __restrict__ Hlast,
                                               const float* __restrict__ W_out,
                                               const float* __restrict__ b_out,
                                               float* __restrict__ out) {
  int k = blockIdx.x >> 2;
  int mc = blockIdx.x & 3;
  int lane = threadIdx.x & 63;
  int wv = threadIdx.x >> 6;
  int m0 = mc * 64 + wv * 16;
  float res[16];
  if (k == 0) {
#pragma unroll
    for (int mi = 0; mi < 16; ++mi) res[mi] = 0.0f;
  } else {
    float acc[16];
#pragma unroll
    for (int i = 0; i < 16; ++i) acc[i] = 0.0f;
    const float* src = Hlast + (size_t)k * L_ * B_;
    for (int j = 0; j < L_; j += 4) {
      float a0 = src[(j + 0) * B_ + lane];
      float a1 = src[(j + 1) * B_ + lane];
      float a2 = src[(j + 2) * B_ + lane];
      float a3 = src[(j + 3) * B_ + lane];
#pragma unroll
      for (int mi = 0; mi < 16; ++mi) {
        float4 wt = *reinterpret_cast<const float4*>(&W_out[(size_t)(m0 + mi) * L_ + j]);
        float t = acc[mi];
        t = fmaf(a0, wt.x, t); t = fmaf(a1, wt.y, t);
        t = fmaf(a2, wt.z, t); t = fmaf(a3, wt.w, t);
        acc[mi] = t;
      }
    }
#pragma unroll
    for (int mi = 0; mi < 16; ++mi) res[mi] = acc[mi] + b_out[m0 + mi];
  }
  float* dst = out + ((size_t)k * B_ + lane) * L_ + m0;
#pragma unroll
  for (int v = 0; v < 4; ++v) {
    float4 t4 = make_float4(res[4 * v], res[4 * v + 1], res[4 * v + 2], res[4 * v + 3]);
    *reinterpret_cast<float4*>(&dst[4 * v]) = t4;
  }
}

// ------------------------------ launcher -----------------------------------
extern "C" void kernel_launch(void* const* d_in, const int* in_sizes, int n_in,
                              void* d_out, int out_size, void* d_ws, size_t ws_size,
                              hipStream_t stream) {
  const float* obsrv = (const float*)d_in[0];
  const float* z0    = (const float*)d_in[1];
  const float* W_emb = (const float*)d_in[2];
  const float* b_emb = (const float*)d_in[3];
  const float* Wx1   = (const float*)d_in[4];
  const float* bx1   = (const float*)d_in[5];
  const float* Wx2   = (const float*)d_in[6];
  const float* bx2   = (const float*)d_in[7];
  const float* Wx3   = (const float*)d_in[8];
  const float* bx3   = (const float*)d_in[9];
  const float* W_ih  = (const float*)d_in[10];
  const float* W_hh  = (const float*)d_in[11];
  const float* b_ih  = (const float*)d_in[12];
  const float* b_hh  = (const float*)d_in[13];
  const float* W_out = (const float*)d_in[14];
  const float* b_out = (const float*)d_in[15];
  float* out = (float*)d_out;
  float* ws = (float*)d_ws;

  if (ws_size < (size_t)WS_FLOATS * sizeof(float)) return;  // fail loud (wrong output)

  float* E_mlp   = ws + E_MLP_OFF;
  float* h_state = ws + H_STATE_OFF;
  float* c_state = ws + C_STATE_OFF;
  float* h_emb   = ws + H_EMB_OFF;
  float* Hlast   = ws + HLAST_OFF;

  k_init<<<(NL_ * L_ * B_) / 256, 256, 0, stream>>>(z0, h_state, c_state);
  k_mlp1<<<255 * 4, 256, 0, stream>>>(obsrv, Wx1, bx1, Hlast);  // Hlast as e1 temp
  k_mlp2<<<255, 256, 0, stream>>>(Hlast, Wx2, bx2, Wx3, bx3, E_mlp);

  for (int d = 1; d <= (255 + NL_ - 1); ++d) {
    int lmin = (d - 255 > 0) ? (d - 255) : 0;
    int lmax = (d - 1 < NL_ - 1) ? (d - 1) : (NL_ - 1);
    int nc = lmax - lmin + 1;
    k_emb<<<nc * 4, 256, 0, stream>>>(h_state, W_emb, b_emb, h_emb, d, lmin);
    k_gates<<<nc * 16, 256, 0, stream>>>(h_state, c_state, h_emb, E_mlp,
                                         W_ih, W_hh, b_ih, b_hh, Hlast, d, lmin);
  }

  k_final<<<S_ * 4, 256, 0, stream>>>(Hlast, W_out, b_out, out);
}